// Round 1
// baseline (251.141 us; speedup 1.0000x reference)
//
#include <hip/hip_runtime.h>
#include <hip/hip_bf16.h>

#define NBH 64
#define NSEQ 2048
#define DD 128
#define EPS 1e-6f

typedef __bf16 bf16x8 __attribute__((ext_vector_type(8)));
typedef __bf16 bf16x4 __attribute__((ext_vector_type(4)));
typedef float  f32x4  __attribute__((ext_vector_type(4)));

__device__ __forceinline__ float elu1(float x) {
    // elu(x)+1 = x+1 (x>0), exp(x) (x<=0)
    return x > 0.f ? x + 1.f : __expf(x);
}

// row-dependent XOR swizzle (in units of 8 bf16): conflict-free for both the
// b128 column-writes (d=4c+i per thread) and the b128 MFMA row-reads.
__device__ __forceinline__ int swz(int r) {
    return ((r >> 2) & 7) ^ ((r & 1) << 2);
}

// ---------------------------------------------------------------------------
// Phase 1: partial KV^T.  grid (8, 64) = (256-row chunk, bh), 512 threads.
// part[(bh*8+s)][e][d] = sum over chunk rows n of Vf[n,e]*Kf[n,d]   (fp32)
// LDS: KfT/VfT [128 d-rows][128 n], bf16, XOR-swizzled, single tile of 128
// rows double-pumped (2 tiles per chunk), tile-1 loads prefetched across
// tile-0 MFMA.
// ---------------------------------------------------------------------------
__global__ __launch_bounds__(512, 4) void kv_partial_kernel(
    const float* __restrict__ K, const float* __restrict__ V,
    const float* __restrict__ mask, float* __restrict__ part)
{
    __shared__ __bf16 KfT[128 * 128];   // 32 KB
    __shared__ __bf16 VfT[128 * 128];   // 32 KB

    const int s    = blockIdx.x;   // n-chunk
    const int bh   = blockIdx.y;
    const int b    = bh >> 4;
    const int t    = threadIdx.x;
    const int c    = t & 31;       // staging: col group, d0 = 4c
    const int rg   = t >> 5;       // staging: row group, n = 8*rg .. +7
    const int lane = t & 63;
    const int w    = t >> 6;       // wave 0..7
    const int quad = lane >> 4;
    const int col  = lane & 15;
    const int n0   = s * 256;

    const f32x4* K4   = (const f32x4*)(K + ((size_t)bh * NSEQ + n0) * DD);
    const f32x4* V4   = (const f32x4*)(V + ((size_t)bh * NSEQ + n0) * DD);
    const float* mrow = mask + b * NSEQ + n0;

    f32x4 acc[8];
    #pragma unroll
    for (int nt = 0; nt < 8; ++nt) acc[nt] = (f32x4){0.f, 0.f, 0.f, 0.f};

    // precomputed swizzled LDS read indices (row*128 is 128-aligned, swz<8,
    // k0<128  ->  base|swz then ^k0 gives row*128 + (k0 ^ (swz<<3)))
    const int arow = w * 16 + col;
    const int aidx = (arow * 128) | (swz(arow) << 3);
    int bidx[8];
    #pragma unroll
    for (int nt = 0; nt < 8; ++nt) {
        int r = nt * 16 + col;
        bidx[nt] = (r * 128) | (swz(r) << 3);
    }

    f32x4 kr[8], vr[8];
    float mv[8];

    // convert + transposed LDS write of the registered 128-row tile
    auto stage = [&]() {
        #pragma unroll
        for (int i = 0; i < 4; ++i) {
            bf16x8 kc, vc;
            #pragma unroll
            for (int j = 0; j < 8; ++j) {
                float m = mv[j];
                kc[j] = (__bf16)(elu1(kr[j][i]) * m);
                vc[j] = (__bf16)(vr[j][i] * m);
            }
            int d  = 4 * c + i;
            int wi = d * 128 + 8 * (rg ^ swz(d));
            *(bf16x8*)&KfT[wi] = kc;
            *(bf16x8*)&VfT[wi] = vc;
        }
    };

    auto mfma_tile = [&]() {
        #pragma unroll
        for (int kk = 0; kk < 4; ++kk) {
            int k0 = kk * 32 + quad * 8;
            bf16x8 a = *(bf16x8*)&VfT[aidx ^ k0];
            #pragma unroll
            for (int nt = 0; nt < 8; ++nt) {
                bf16x8 bb = *(bf16x8*)&KfT[bidx[nt] ^ k0];
                acc[nt] = __builtin_amdgcn_mfma_f32_16x16x32_bf16(a, bb, acc[nt], 0, 0, 0);
            }
        }
    };

    // ---- tile 0: load (float4, coalesced 512B/row-segment)
    #pragma unroll
    for (int j = 0; j < 8; ++j) {
        int row = rg * 8 + j;
        kr[j] = K4[row * 32 + c];
        vr[j] = V4[row * 32 + c];
        mv[j] = mrow[row];
    }
    stage();
    __syncthreads();

    // ---- prefetch tile 1 (in flight across tile-0 MFMA + barrier)
    #pragma unroll
    for (int j = 0; j < 8; ++j) {
        int row = 128 + rg * 8 + j;
        kr[j] = K4[row * 32 + c];
        vr[j] = V4[row * 32 + c];
        mv[j] = mrow[row];
    }

    mfma_tile();           // k = 0..127
    __syncthreads();       // all waves done reading tile 0
    stage();               // compiler inserts the vmcnt wait here
    __syncthreads();
    mfma_tile();           // k = 128..255

    // store partial KV^T (fp32), layout [e][d]
    float* po = part + (((size_t)bh * 8 + s) << 14);
    #pragma unroll
    for (int r = 0; r < 4; ++r) {
        int e = w * 16 + quad * 4 + r;
        #pragma unroll
        for (int nt = 0; nt < 8; ++nt)
            po[e * 128 + nt * 16 + col] = acc[nt][r];
    }
}

// ---------------------------------------------------------------------------
// Phase 2: sum 8 partials -> bf16 KVT[bh][e][d].  262144 threads, 4 elems ea.
// ---------------------------------------------------------------------------
__global__ __launch_bounds__(256) void kv_reduce_kernel(
    const float* __restrict__ part, __bf16* __restrict__ kvt)
{
    int gid = blockIdx.x * 256 + threadIdx.x;   // 0..262143
    int i   = gid * 4;
    int bh  = i >> 14;
    int ii  = i & 16383;
    const float* p = part + (((size_t)bh * 8) << 14) + ii;
    f32x4 sum = (f32x4){0.f, 0.f, 0.f, 0.f};
    #pragma unroll
    for (int s = 0; s < 8; ++s)
        sum += *(const f32x4*)(p + ((size_t)s << 14));
    bf16x4 o;
    o[0] = (__bf16)sum[0]; o[1] = (__bf16)sum[1];
    o[2] = (__bf16)sum[2]; o[3] = (__bf16)sum[3];
    *(bf16x4*)&kvt[i] = o;
}

// ---------------------------------------------------------------------------
// Phase 3: out = rmsnorm( Qf @ KV ).  grid (32, 64) = (64-row chunk, bh),
// 256 threads.  Q goes straight from global to the MFMA A-fragment registers
// (each lane's fragment is 8 contiguous floats of its own Q row) -- no Q LDS,
// one barrier, 34 KB LDS -> 4 blocks/CU.
// ---------------------------------------------------------------------------
__global__ __launch_bounds__(256, 4) void qkv_norm_kernel(
    const float* __restrict__ Q, const __bf16* __restrict__ kvt,
    float* __restrict__ out)
{
    __shared__ __bf16 KVT[128 * 136];

    const int bh   = blockIdx.y;
    const int row0 = blockIdx.x * 64;
    const int t    = threadIdx.x;
    const int lane = t & 63;
    const int w    = t >> 6;     // wave 0..3 -> rows [w*16, +16)
    const int quad = lane >> 4;
    const int col  = lane & 15;

    // issue Q loads first (HBM, longest latency): lane owns one row, reads
    // its quad's 8-float slices for all 4 k-steps.
    const int row = row0 + w * 16 + col;
    const f32x4* q4 = (const f32x4*)(Q + ((size_t)bh * NSEQ + row) * DD);
    f32x4 qr[8];
    #pragma unroll
    for (int kk = 0; kk < 4; ++kk) {
        qr[2 * kk]     = q4[kk * 8 + quad * 2];
        qr[2 * kk + 1] = q4[kk * 8 + quad * 2 + 1];
    }

    // stage KVT (bf16, 128x128) into padded LDS (stride 136: read/write at
    // bank floor)
    {
        const __bf16* src = kvt + ((size_t)bh << 14);
        #pragma unroll
        for (int i = 0; i < 8; ++i) {
            int idx = i * 256 + t;
            int e   = idx >> 4;
            int dd  = (idx & 15) * 8;
            *(bf16x8*)&KVT[e * 136 + dd] = *(const bf16x8*)&src[e * 128 + dd];
        }
    }
    __syncthreads();

    // elu + convert Q fragments in-register
    bf16x8 a[4];
    #pragma unroll
    for (int kk = 0; kk < 4; ++kk) {
        #pragma unroll
        for (int h = 0; h < 2; ++h) {
            f32x4 q = qr[2 * kk + h];
            #pragma unroll
            for (int u = 0; u < 4; ++u)
                a[kk][h * 4 + u] = (__bf16)elu1(q[u]);
        }
    }

    f32x4 acc[8];
    #pragma unroll
    for (int et = 0; et < 8; ++et) acc[et] = (f32x4){0.f, 0.f, 0.f, 0.f};

    #pragma unroll
    for (int kk = 0; kk < 4; ++kk) {
        int k0 = kk * 32 + quad * 8;
        #pragma unroll
        for (int et = 0; et < 8; ++et) {
            bf16x8 bb = *(bf16x8*)&KVT[(et * 16 + col) * 136 + k0];
            acc[et] = __builtin_amdgcn_mfma_f32_16x16x32_bf16(a[kk], bb, acc[et], 0, 0, 0);
        }
    }

    // RMS norm per row + store.  C layout: row = quad*4+reg, col = lane&15.
    float* ob = out + ((size_t)bh * NSEQ + row0) * DD;
    #pragma unroll
    for (int r = 0; r < 4; ++r) {
        float p = 0.f;
        #pragma unroll
        for (int et = 0; et < 8; ++et) p += acc[et][r] * acc[et][r];
        p += __shfl_xor(p, 1);
        p += __shfl_xor(p, 2);
        p += __shfl_xor(p, 4);
        p += __shfl_xor(p, 8);   // sum over the 16 lanes holding this row
        float scale = rsqrtf(p * (1.0f / 128.0f) + EPS);
        int orow = w * 16 + quad * 4 + r;
        #pragma unroll
        for (int et = 0; et < 8; ++et)
            ob[orow * DD + et * 16 + col] = acc[et][r] * scale;
    }
}

extern "C" void kernel_launch(void* const* d_in, const int* in_sizes, int n_in,
                              void* d_out, int out_size, void* d_ws, size_t ws_size,
                              hipStream_t stream) {
    const float* Q    = (const float*)d_in[0];
    const float* K    = (const float*)d_in[1];
    const float* V    = (const float*)d_in[2];
    const float* mask = (const float*)d_in[3];
    float* out = (float*)d_out;

    float*  part = (float*)d_ws;                                   // 32 MB
    __bf16* kvt  = (__bf16*)((char*)d_ws + (size_t)NBH * 8 * 16384 * 4);

    kv_partial_kernel<<<dim3(8, NBH), 512, 0, stream>>>(K, V, mask, part);
    kv_reduce_kernel<<<1024, 256, 0, stream>>>(part, kvt);
    qkv_norm_kernel<<<dim3(32, NBH), 256, 0, stream>>>(Q, kvt, out);
}

// Round 2
// 236.562 us; speedup vs baseline: 1.0616x; 1.0616x over previous
//
#include <hip/hip_runtime.h>
#include <hip/hip_bf16.h>

#define NBH 64
#define NSEQ 2048
#define DD 128
#define EPS 1e-6f

typedef __bf16 bf16x8 __attribute__((ext_vector_type(8)));
typedef __bf16 bf16x4 __attribute__((ext_vector_type(4)));
typedef float  f32x4  __attribute__((ext_vector_type(4)));

__device__ __forceinline__ float elu1(float x) {
    // elu(x)+1 = x+1 (x>0), exp(x) (x<=0)
    return x > 0.f ? x + 1.f : __expf(x);
}

// row-dependent XOR swizzle (units of 8 bf16 = 16 B slot).  For 64-elem
// (128 B) LDS rows every row starts at bank 0; XOR-ing the 16B-slot index
// with swz(row) makes column-writes (d = 4c+i) and MFMA row-reads all
// uniform 8 lanes/slot = wave64 b128 floor.
__device__ __forceinline__ int swz(int r) {
    return ((r >> 2) & 7) ^ ((r & 1) << 2);
}

// ---------------------------------------------------------------------------
// Phase 1: partial KV^T.  grid (8, 64) = (256-row chunk, bh), 512 threads.
// part[(bh*8+s)][e][d] = sum over chunk rows n of Vf[n,e]*Kf[n,d]   (fp32)
// 64-row tiles, double-buffered LDS (4 x 16 KB), register prefetch of tile
// t+1 in flight across tile-t MFMA, one barrier per tile.
// Threads t<256 stage K, t>=256 stage V (8 f32x4 prefetch each -> no spill
// under the 128-VGPR cap; R1's 128-row prefetch spilled ~33 MB to scratch).
// ---------------------------------------------------------------------------
__global__ __launch_bounds__(512, 4) void kv_partial_kernel(
    const float* __restrict__ K, const float* __restrict__ V,
    const float* __restrict__ mask, float* __restrict__ part)
{
    __shared__ __bf16 KfT[2][128 * 64];   // [buf][d][n]  16 KB each
    __shared__ __bf16 VfT[2][128 * 64];   // [buf][e][n]
    __shared__ float  mloc[256];

    const int s    = blockIdx.x;   // n-chunk
    const int bh   = blockIdx.y;
    const int b    = bh >> 4;
    const int t    = threadIdx.x;
    const int lane = t & 63;
    const int w    = t >> 6;       // wave 0..7
    const int quad = lane >> 4;
    const int col  = lane & 15;
    const int n0   = s * 256;

    // staging role: K-half / V-half (wave-uniform)
    const int isV = t >> 8;
    const int c   = t & 31;        // d-group: d = 4c+i
    const int rg  = (t >> 5) & 7;  // rows rg*8 .. rg*8+7 within 64-row tile

    const f32x4* S4 = (const f32x4*)((isV ? V : K) + ((size_t)bh * NSEQ + n0) * DD);
    __bf16* myT = isV ? &VfT[0][0] : &KfT[0][0];

    f32x4 acc[8];
    #pragma unroll
    for (int nt = 0; nt < 8; ++nt) acc[nt] = (f32x4){0.f, 0.f, 0.f, 0.f};

    // swizzled MFMA read indices (row stride 64 elems; swz in bits 3-5)
    const int arow = w * 16 + col;
    const int aidx = arow * 64 + (swz(arow) << 3);
    int bidx[8];
    #pragma unroll
    for (int nt = 0; nt < 8; ++nt) {
        int r = nt * 16 + col;
        bidx[nt] = r * 64 + (swz(r) << 3);
    }

    f32x4 xr[8];   // prefetch: 8 rows x 4 d  (32 VGPRs)

    auto load_tile = [&](int tile) {
        #pragma unroll
        for (int j = 0; j < 8; ++j)
            xr[j] = S4[(tile * 64 + rg * 8 + j) * 32 + c];
    };

    auto stage = [&](int buf, int tile) {
        float ml[8];
        #pragma unroll
        for (int j = 0; j < 8; ++j) ml[j] = mloc[tile * 64 + rg * 8 + j];  // broadcast
        __bf16* dst = myT + buf * (128 * 64);
        #pragma unroll
        for (int i = 0; i < 4; ++i) {
            bf16x8 xc;
            if (!isV) {
                #pragma unroll
                for (int j = 0; j < 8; ++j) xc[j] = (__bf16)(elu1(xr[j][i]) * ml[j]);
            } else {
                #pragma unroll
                for (int j = 0; j < 8; ++j) xc[j] = (__bf16)(xr[j][i] * ml[j]);
            }
            int d = 4 * c + i;
            *(bf16x8*)&dst[d * 64 + ((rg ^ swz(d)) << 3)] = xc;
        }
    };

    auto mfma_tile = [&](int buf) {
        const __bf16* Vb = &VfT[buf][0];
        const __bf16* Kb = &KfT[buf][0];
        #pragma unroll
        for (int kk = 0; kk < 2; ++kk) {
            int k0 = kk * 32 + quad * 8;
            bf16x8 a = *(bf16x8*)&Vb[aidx ^ k0];
            #pragma unroll
            for (int nt = 0; nt < 8; ++nt) {
                bf16x8 bb = *(bf16x8*)&Kb[bidx[nt] ^ k0];
                acc[nt] = __builtin_amdgcn_mfma_f32_16x16x32_bf16(a, bb, acc[nt], 0, 0, 0);
            }
        }
    };

    // prologue: issue mask + tile-0 loads, fill mloc, stage tile 0
    float mf = 0.f;
    if (t < 256) mf = mask[b * NSEQ + n0 + t];
    load_tile(0);
    if (t < 256) mloc[t] = mf;
    __syncthreads();               // mloc visible
    stage(0, 0);
    __syncthreads();               // tile 0 staged

    // pipelined main loop: 1 barrier/tile, loads overlap MFMA
    #pragma unroll
    for (int tile = 0; tile < 4; ++tile) {
        if (tile < 3) load_tile(tile + 1);        // prefetch (in flight)
        mfma_tile(tile & 1);
        if (tile < 3) {
            stage((tile + 1) & 1, tile + 1);      // waits for prefetch here
            __syncthreads();
        }
    }

    // store partial KV^T (fp32), layout [e][d]
    float* po = part + (((size_t)bh * 8 + s) << 14);
    #pragma unroll
    for (int r = 0; r < 4; ++r) {
        int e = w * 16 + quad * 4 + r;
        #pragma unroll
        for (int nt = 0; nt < 8; ++nt)
            po[e * 128 + nt * 16 + col] = acc[nt][r];
    }
}

// ---------------------------------------------------------------------------
// Phase 2: sum 8 partials -> bf16 KVT[bh][e][d].  262144 threads, 4 elems ea.
// ---------------------------------------------------------------------------
__global__ __launch_bounds__(256) void kv_reduce_kernel(
    const float* __restrict__ part, __bf16* __restrict__ kvt)
{
    int gid = blockIdx.x * 256 + threadIdx.x;   // 0..262143
    int i   = gid * 4;
    int bh  = i >> 14;
    int ii  = i & 16383;
    const float* p = part + (((size_t)bh * 8) << 14) + ii;
    f32x4 sum = (f32x4){0.f, 0.f, 0.f, 0.f};
    #pragma unroll
    for (int s = 0; s < 8; ++s)
        sum += *(const f32x4*)(p + ((size_t)s << 14));
    bf16x4 o;
    o[0] = (__bf16)sum[0]; o[1] = (__bf16)sum[1];
    o[2] = (__bf16)sum[2]; o[3] = (__bf16)sum[3];
    *(bf16x4*)&kvt[i] = o;
}

// ---------------------------------------------------------------------------
// Phase 3: out = rmsnorm( Qf @ KV ).  grid (32, 64) = (64-row chunk, bh),
// 256 threads.  Q goes straight from global to the MFMA A-fragment registers
// (each lane's fragment is 8 contiguous floats of its own Q row) -- no Q LDS,
// one barrier, 34 KB LDS -> 4 blocks/CU.
// ---------------------------------------------------------------------------
__global__ __launch_bounds__(256, 4) void qkv_norm_kernel(
    const float* __restrict__ Q, const __bf16* __restrict__ kvt,
    float* __restrict__ out)
{
    __shared__ __bf16 KVT[128 * 136];

    const int bh   = blockIdx.y;
    const int row0 = blockIdx.x * 64;
    const int t    = threadIdx.x;
    const int lane = t & 63;
    const int w    = t >> 6;     // wave 0..3 -> rows [w*16, +16)
    const int quad = lane >> 4;
    const int col  = lane & 15;

    // issue Q loads first (HBM, longest latency): lane owns one row, reads
    // its quad's 8-float slices for all 4 k-steps.
    const int row = row0 + w * 16 + col;
    const f32x4* q4 = (const f32x4*)(Q + ((size_t)bh * NSEQ + row) * DD);
    f32x4 qr[8];
    #pragma unroll
    for (int kk = 0; kk < 4; ++kk) {
        qr[2 * kk]     = q4[kk * 8 + quad * 2];
        qr[2 * kk + 1] = q4[kk * 8 + quad * 2 + 1];
    }

    // stage KVT (bf16, 128x128) into padded LDS (stride 136)
    {
        const __bf16* src = kvt + ((size_t)bh << 14);
        #pragma unroll
        for (int i = 0; i < 8; ++i) {
            int idx = i * 256 + t;
            int e   = idx >> 4;
            int dd  = (idx & 15) * 8;
            *(bf16x8*)&KVT[e * 136 + dd] = *(const bf16x8*)&src[e * 128 + dd];
        }
    }
    __syncthreads();

    // elu + convert Q fragments in-register
    bf16x8 a[4];
    #pragma unroll
    for (int kk = 0; kk < 4; ++kk) {
        #pragma unroll
        for (int h = 0; h < 2; ++h) {
            f32x4 q = qr[2 * kk + h];
            #pragma unroll
            for (int u = 0; u < 4; ++u)
                a[kk][h * 4 + u] = (__bf16)elu1(q[u]);
        }
    }

    f32x4 acc[8];
    #pragma unroll
    for (int et = 0; et < 8; ++et) acc[et] = (f32x4){0.f, 0.f, 0.f, 0.f};

    #pragma unroll
    for (int kk = 0; kk < 4; ++kk) {
        int k0 = kk * 32 + quad * 8;
        #pragma unroll
        for (int et = 0; et < 8; ++et) {
            bf16x8 bb = *(bf16x8*)&KVT[(et * 16 + col) * 136 + k0];
            acc[et] = __builtin_amdgcn_mfma_f32_16x16x32_bf16(a[kk], bb, acc[et], 0, 0, 0);
        }
    }

    // RMS norm per row + store.  C layout: row = quad*4+reg, col = lane&15.
    float* ob = out + ((size_t)bh * NSEQ + row0) * DD;
    #pragma unroll
    for (int r = 0; r < 4; ++r) {
        float p = 0.f;
        #pragma unroll
        for (int et = 0; et < 8; ++et) p += acc[et][r] * acc[et][r];
        p += __shfl_xor(p, 1);
        p += __shfl_xor(p, 2);
        p += __shfl_xor(p, 4);
        p += __shfl_xor(p, 8);   // sum over the 16 lanes holding this row
        float scale = rsqrtf(p * (1.0f / 128.0f) + EPS);
        int orow = w * 16 + quad * 4 + r;
        #pragma unroll
        for (int et = 0; et < 8; ++et)
            ob[orow * DD + et * 16 + col] = acc[et][r] * scale;
    }
}

extern "C" void kernel_launch(void* const* d_in, const int* in_sizes, int n_in,
                              void* d_out, int out_size, void* d_ws, size_t ws_size,
                              hipStream_t stream) {
    const float* Q    = (const float*)d_in[0];
    const float* K    = (const float*)d_in[1];
    const float* V    = (const float*)d_in[2];
    const float* mask = (const float*)d_in[3];
    float* out = (float*)d_out;

    float*  part = (float*)d_ws;                                   // 32 MB
    __bf16* kvt  = (__bf16*)((char*)d_ws + (size_t)NBH * 8 * 16384 * 4);

    kv_partial_kernel<<<dim3(8, NBH), 512, 0, stream>>>(K, V, mask, part);
    kv_reduce_kernel<<<1024, 256, 0, stream>>>(part, kvt);
    qkv_norm_kernel<<<dim3(32, NBH), 256, 0, stream>>>(Q, kvt, out);
}